// Round 16
// baseline (15.564 us; speedup 1.0000x reference)
//
#include <hip/hip_runtime.h>

// Problem constants (from reference)
#define N_ 16
#define A_ 4096
#define G_ 256
#define C_ 80
#define BIG_ 1e8f
#define BIAS_ 2e8f
#define LN2_ 0.69314718055994531f

// Round 16: LDS-traffic halving + pk-packed distance on the R15 geometry.
//  - staging stores NEGATED, mask-folded boxes: x' = -(x + (mask?0:2e8)),
//    y'z'w' = -yzw. Distance |p - b| == |p + b'| bitwise (same sub). Masked
//    boxes give d ~ 2e8 > BIG -> never win; nonempty <=> dmin < BIG; when
//    nonempty the winner is unmasked so cb (negated) is exact for pd too:
//    pd = sum |q + cb'|.
//  - box-outer DUAL-ANCHOR sweep: one ds_read_b128 per box feeds BOTH of the
//    group's anchors -> LDS reads/wave halved (32 -> 16); only the current
//    box is live (4 VGPR), keeping total VGPR <= 64 = 8 waves/SIMD.
//  - v_pk_add_f32 (VOP3P, no modifiers needed thanks to pre-negation):
//    distance = 2 pk_add + 3 abs-mod adds = 5 arith/box/anchor (was 7).
//  - DPP butterflies, branchless focal, register corr-select: unchanged.
// Geometry: 2048 blocks x 256 thr (one co-resident generation, 32 waves/CU),
// 32 anchors/block, 16 groups x 2 anchors.

#define DPP_XOR1  0xB1   // quad_perm(1,0,3,2)
#define DPP_XOR2  0x4E   // quad_perm(2,3,0,1)
#define DPP_XOR7  0x141  // row_half_mirror
#define DPP_XOR15 0x140  // row_mirror

typedef float f2 __attribute__((ext_vector_type(2)));

template<int CTRL>
__device__ __forceinline__ float dppf(float x) {
    return __int_as_float(__builtin_amdgcn_update_dpp(
        0, __float_as_int(x), CTRL, 0xF, 0xF, true));
}
template<int CTRL>
__device__ __forceinline__ int dppi(int x) {
    return __builtin_amdgcn_update_dpp(0, x, CTRL, 0xF, 0xF, true);
}
template<int CTRL>
__device__ __forceinline__ void argmin_stage(float& d, int& idx) {
    const float od = dppf<CTRL>(d);
    const int   oc = dppi<CTRL>(idx);
    const bool  bt = (od < d) || (od == d && oc < idx);
    d   = bt ? od : d;
    idx = bt ? oc : idx;
}

// p + b' per packed pair (b' pre-negated)
__device__ __forceinline__ f2 pkadd(f2 a, f2 b) {
    f2 r;
    asm("v_pk_add_f32 %0, %1, %2" : "=v"(r) : "v"(a), "v"(b));
    return r;
}

__global__ __launch_bounds__(256, 4) void cbppl_fused_kernel(
    const float* __restrict__ gt_padded,    // (N, G, 4)
    const float* __restrict__ prop_boxes,   // (N, A, 4)
    const float* __restrict__ pred_boxes,   // (N, A, 4)
    const float* __restrict__ class_logits, // (N, A, C)
    const int*   __restrict__ gt_masks,     // (N, G) bool->int32
    const int*   __restrict__ gt_classes,   // (N, G)
    float* __restrict__ out_cls,            // (N, A)
    float* __restrict__ out_proj)           // (N, A)
{
    __shared__ float4 s_gt[G_];   // negated, mask-folded
    __shared__ int    s_cls[G_];

    const int t   = threadIdx.x;
    const int sub = t & 15;                  // lane-in-group
    const int gid = t >> 4;                  // group 0..15 within block
    const int n   = blockIdx.x >> 7;         // 128 blocks per batch
    const int ab  = (blockIdx.x & 127) << 5; // 32 anchors per block

    // ---- one-time: stage negated, mask-folded gt boxes + classes ----
    {
        const int gidx = n * G_ + t;        // t == g (256 threads)
        float4 g4 = ((const float4*)gt_padded)[gidx];
        const float bias = gt_masks[gidx] ? 0.0f : BIAS_;
        g4.x = -(g4.x + bias);
        g4.y = -g4.y; g4.z = -g4.z; g4.w = -g4.w;
        s_gt[t]  = g4;
        s_cls[t] = gt_classes[gidx];
    }
    __syncthreads();

    // ---- two anchors per group ----
    const int row0 = n * A_ + ab + gid;        // pass-0 anchor
    const int row1 = row0 + 16;                // pass-1 anchor

    const float4 pbv0 = ((const float4*)prop_boxes)[row0];
    const float4 pbv1 = ((const float4*)prop_boxes)[row1];
    const f2 p0lo = {pbv0.x, pbv0.y}, p0hi = {pbv0.z, pbv0.w};
    const f2 p1lo = {pbv1.x, pbv1.y}, p1hi = {pbv1.z, pbv1.w};

    // ---- box-outer dual-anchor argmin: ONE ds_read per box, both anchors ----
    float d0 = INFINITY, d1 = INFINITY;
    int   m0 = 0,        m1 = 0;
    #pragma unroll
    for (int m = 0; m < 16; ++m) {
        const float4 bb = s_gt[sub + (m << 4)];
        const f2 blo = {bb.x, bb.y}, bhi = {bb.z, bb.w};

        const f2 ta = pkadd(p0lo, blo), tb = pkadd(p0hi, bhi);
        const float da = (fabsf(ta.x) + fabsf(ta.y))
                       + (fabsf(tb.x) + fabsf(tb.y));
        if (da < d0) { d0 = da; m0 = m; }      // lower m = lower g

        const f2 tc = pkadd(p1lo, blo), td = pkadd(p1hi, bhi);
        const float db = (fabsf(tc.x) + fabsf(tc.y))
                       + (fabsf(td.x) + fabsf(td.y));
        if (db < d1) { d1 = db; m1 = m; }
    }
    int i0 = (m0 << 4) + sub;                  // g index, anchor 0
    int i1 = (m1 << 4) + sub;                  // g index, anchor 1

    // 16-lane argmin butterflies on DPP (VALU pipe)
    argmin_stage<DPP_XOR1 >(d0, i0);  argmin_stage<DPP_XOR1 >(d1, i1);
    argmin_stage<DPP_XOR2 >(d0, i0);  argmin_stage<DPP_XOR2 >(d1, i1);
    argmin_stage<DPP_XOR7 >(d0, i0);  argmin_stage<DPP_XOR7 >(d1, i1);
    argmin_stage<DPP_XOR15>(d0, i0);  argmin_stage<DPP_XOR15>(d1, i1);

    // ---- per-anchor epilogue (focal + proj + stores) ----
    #pragma unroll
    for (int p = 0; p < 2; ++p) {
        const int   row      = p ? row1 : row0;
        const int   closest  = p ? i1 : i0;
        const int   nonempty = (p ? d1 : d0) < BIG_;

        const float4 cb     = s_gt[closest];   // negated; exact when nonempty
        const int    target = s_cls[closest];

        const float4 qb = ((const float4*)pred_boxes)[row];
        const float  pd = fabsf(qb.x + cb.x) + fabsf(qb.y + cb.y)
                        + fabsf(qb.z + cb.z) + fabsf(qb.w + cb.w);

        const float* lrow = class_logits + (size_t)row * C_;
        float xv[5];
        #pragma unroll
        for (int k = 0; k < 5; ++k) xv[k] = lrow[sub + (k << 4)];

        // focal, negative-class closed form (branchless; exact identities)
        float acc = 0.0f;
        #pragma unroll
        for (int j = 0; j < 5; ++j) {
            const float x  = xv[j];
            const float u  = __expf(-x);
            const float tt = 1.0f + u;
            const float sp = fmaf(LN2_, __log2f(tt), x);
            const float r  = __builtin_amdgcn_rcpf(tt);
            acc = fmaf(sp, r * r, acc);
        }
        acc *= 0.75f;

        // target-class correction; xt selected from registers (kt uniform)
        {
            const int kt = target >> 4;
            float xt = xv[0];
            xt = (kt == 1) ? xv[1] : xt;
            xt = (kt == 2) ? xv[2] : xt;
            xt = (kt == 3) ? xv[3] : xt;
            xt = (kt == 4) ? xv[4] : xt;
            const float u  = __expf(-xt);
            const float tt = 1.0f + u;
            const float sp = fmaf(LN2_, __log2f(tt), xt);
            const float pp = __builtin_amdgcn_rcpf(tt);
            const float q  = 1.0f - pp;
            const float corr = fmaf(0.25f * (sp - xt), q * q,
                                    -0.75f * sp * pp * pp);
            acc += ((target & 15) == sub) ? corr : 0.0f;  // owner lane adds
        }

        // group sum of focal partials on DPP
        acc += dppf<DPP_XOR1 >(acc);
        acc += dppf<DPP_XOR2 >(acc);
        acc += dppf<DPP_XOR7 >(acc);
        acc += dppf<DPP_XOR15>(acc);

        if (sub == 0) {
            out_cls[row]  = nonempty ? acc * (1.0f / (float)C_) : 0.0f;
            out_proj[row] = nonempty ? pd : 0.0f;
        }
    }
}

extern "C" void kernel_launch(void* const* d_in, const int* in_sizes, int n_in,
                              void* d_out, int out_size, void* d_ws, size_t ws_size,
                              hipStream_t stream) {
    const float* gt_padded    = (const float*)d_in[0];
    const float* prop_boxes   = (const float*)d_in[1];
    const float* pred_boxes   = (const float*)d_in[2];
    const float* class_logits = (const float*)d_in[3];
    const int*   gt_masks     = (const int*)d_in[4];
    const int*   gt_classes   = (const int*)d_in[5];

    float* out = (float*)d_out;
    float* out_cls  = out;             // classification_loss, (N, A)
    float* out_proj = out + N_ * A_;   // projection_loss,     (N, A)

    dim3 grid(N_ * A_ / 32);           // 2048 blocks = one generation
    dim3 block(256);
    cbppl_fused_kernel<<<grid, block, 0, stream>>>(
        gt_padded, prop_boxes, pred_boxes, class_logits,
        gt_masks, gt_classes, out_cls, out_proj);
}

// Round 17
// 14.930 us; speedup vs baseline: 1.0425x; 1.0425x over previous
//
#include <hip/hip_runtime.h>

// Problem constants (from reference)
#define N_ 16
#define A_ 4096
#define G_ 256
#define C_ 80
#define BIG_ 1e8f
#define LN2_ 0.69314718055994531f

// Round 17: merged dual-anchor box sweep, confounders removed.
// R16 regression diagnosed as (a) logit loads moved late -> latency exposed,
// (b) inline-asm pk_add blocked scheduling. This round keeps the merged
// sweep (one ds_read_b128 per box feeds BOTH anchors: hot-loop LDS reads
// halved vs R15) but restores R15's early load schedule (logits + prop
// boxes hoisted before staging) and plain fabsf math (sub + abs-modifier
// add, scheduler-friendly, 2-way ILP across anchors).
// Geometry: R15 exact — 2048 blocks x 256 thr (one co-resident generation,
// 8 waves/SIMD at the natural 64-VGPR allocation), 32 anchors/block,
// 16 groups x 2 anchors. Masked-out boxes staged as (BIG,...): never win;
// nonempty <=> dmin < BIG. DPP butterflies; branchless focal (absmax 0.0).

#define DPP_XOR1  0xB1   // quad_perm(1,0,3,2)
#define DPP_XOR2  0x4E   // quad_perm(2,3,0,1)
#define DPP_XOR7  0x141  // row_half_mirror
#define DPP_XOR15 0x140  // row_mirror

template<int CTRL>
__device__ __forceinline__ float dppf(float x) {
    return __int_as_float(__builtin_amdgcn_update_dpp(
        0, __float_as_int(x), CTRL, 0xF, 0xF, true));
}
template<int CTRL>
__device__ __forceinline__ int dppi(int x) {
    return __builtin_amdgcn_update_dpp(0, x, CTRL, 0xF, 0xF, true);
}
template<int CTRL>
__device__ __forceinline__ void argmin_stage(float& d, int& idx) {
    const float od = dppf<CTRL>(d);
    const int   oc = dppi<CTRL>(idx);
    const bool  bt = (od < d) || (od == d && oc < idx);
    d   = bt ? od : d;
    idx = bt ? oc : idx;
}

__global__ __launch_bounds__(256, 4) void cbppl_fused_kernel(
    const float* __restrict__ gt_padded,    // (N, G, 4)
    const float* __restrict__ prop_boxes,   // (N, A, 4)
    const float* __restrict__ pred_boxes,   // (N, A, 4)
    const float* __restrict__ class_logits, // (N, A, C)
    const int*   __restrict__ gt_masks,     // (N, G) bool->int32
    const int*   __restrict__ gt_classes,   // (N, G)
    float* __restrict__ out_cls,            // (N, A)
    float* __restrict__ out_proj)           // (N, A)
{
    __shared__ float4 s_gt[G_];
    __shared__ int    s_cls[G_];

    const int t   = threadIdx.x;
    const int sub = t & 15;                  // lane-in-group
    const int gid = t >> 4;                  // group 0..15 within block
    const int n   = blockIdx.x >> 7;         // 128 blocks per batch
    const int ab  = (blockIdx.x & 127) << 5; // 32 anchors per block

    const int row0 = n * A_ + ab + gid;      // anchor 0
    const int row1 = row0 + 16;              // anchor 1

    // ---- hoisted loads: prop boxes + all logits (latency hides under
    //      staging + argmin) ----
    const float4 pb0 = ((const float4*)prop_boxes)[row0];
    const float4 pb1 = ((const float4*)prop_boxes)[row1];
    const float* lr0 = class_logits + (size_t)row0 * C_;
    const float* lr1 = class_logits + (size_t)row1 * C_;
    float xv0[5], xv1[5];
    #pragma unroll
    for (int k = 0; k < 5; ++k) xv0[k] = lr0[sub + (k << 4)];
    #pragma unroll
    for (int k = 0; k < 5; ++k) xv1[k] = lr1[sub + (k << 4)];

    // ---- stage masked gt boxes + classes to LDS ----
    {
        const int gidx = n * G_ + t;        // t == g (256 threads)
        float4 g4 = ((const float4*)gt_padded)[gidx];
        if (!gt_masks[gidx]) { g4.x = BIG_; g4.y = BIG_; g4.z = BIG_; g4.w = BIG_; }
        s_gt[t]  = g4;
        s_cls[t] = gt_classes[gidx];
    }
    __syncthreads();

    // ---- merged box sweep: ONE ds_read per box feeds BOTH anchors ----
    float d0 = INFINITY, d1 = INFINITY;
    int   m0 = 0,        m1 = 0;
    #pragma unroll
    for (int m = 0; m < 16; ++m) {
        const float4 bb = s_gt[sub + (m << 4)];
        const float da = fabsf(pb0.x - bb.x) + fabsf(pb0.y - bb.y)
                       + fabsf(pb0.z - bb.z) + fabsf(pb0.w - bb.w);
        const float db = fabsf(pb1.x - bb.x) + fabsf(pb1.y - bb.y)
                       + fabsf(pb1.z - bb.z) + fabsf(pb1.w - bb.w);
        if (da < d0) { d0 = da; m0 = m; }    // lower m = lower g
        if (db < d1) { d1 = db; m1 = m; }
    }
    int i0 = (m0 << 4) + sub;                // g index, anchor 0
    int i1 = (m1 << 4) + sub;                // g index, anchor 1

    // 16-lane argmin butterflies on DPP (VALU pipe; two chains interleave)
    argmin_stage<DPP_XOR1 >(d0, i0);  argmin_stage<DPP_XOR1 >(d1, i1);
    argmin_stage<DPP_XOR2 >(d0, i0);  argmin_stage<DPP_XOR2 >(d1, i1);
    argmin_stage<DPP_XOR7 >(d0, i0);  argmin_stage<DPP_XOR7 >(d1, i1);
    argmin_stage<DPP_XOR15>(d0, i0);  argmin_stage<DPP_XOR15>(d1, i1);

    // ---- per-anchor epilogue ----
    #pragma unroll
    for (int p = 0; p < 2; ++p) {
        const int   row      = p ? row1 : row0;
        const int   closest  = p ? i1 : i0;
        const int   nonempty = (p ? d1 : d0) < BIG_;

        // qb load issued here; latency hides under the focal trans chain
        const float4 qb     = ((const float4*)pred_boxes)[row];
        const float4 cb     = s_gt[closest];     // group-uniform broadcast
        const int    target = s_cls[closest];

        // focal, negative-class closed form (branchless; exact identities)
        float acc = 0.0f;
        #pragma unroll
        for (int j = 0; j < 5; ++j) {
            const float x  = p ? xv1[j] : xv0[j];
            const float u  = __expf(-x);
            const float tt = 1.0f + u;
            const float sp = fmaf(LN2_, __log2f(tt), x);
            const float r  = __builtin_amdgcn_rcpf(tt);
            acc = fmaf(sp, r * r, acc);
        }
        acc *= 0.75f;

        // target-class correction; xt selected from registers (kt uniform)
        {
            const int kt = target >> 4;
            float xt = p ? xv1[0] : xv0[0];
            xt = (kt == 1) ? (p ? xv1[1] : xv0[1]) : xt;
            xt = (kt == 2) ? (p ? xv1[2] : xv0[2]) : xt;
            xt = (kt == 3) ? (p ? xv1[3] : xv0[3]) : xt;
            xt = (kt == 4) ? (p ? xv1[4] : xv0[4]) : xt;
            const float u  = __expf(-xt);
            const float tt = 1.0f + u;
            const float sp = fmaf(LN2_, __log2f(tt), xt);
            const float pp = __builtin_amdgcn_rcpf(tt);
            const float q  = 1.0f - pp;
            const float corr = fmaf(0.25f * (sp - xt), q * q,
                                    -0.75f * sp * pp * pp);
            acc += ((target & 15) == sub) ? corr : 0.0f;  // owner lane adds
        }

        // group sum of focal partials on DPP
        acc += dppf<DPP_XOR1 >(acc);
        acc += dppf<DPP_XOR2 >(acc);
        acc += dppf<DPP_XOR7 >(acc);
        acc += dppf<DPP_XOR15>(acc);

        const float pd = fabsf(qb.x - cb.x) + fabsf(qb.y - cb.y)
                       + fabsf(qb.z - cb.z) + fabsf(qb.w - cb.w);

        if (sub == 0) {
            out_cls[row]  = nonempty ? acc * (1.0f / (float)C_) : 0.0f;
            out_proj[row] = nonempty ? pd : 0.0f;
        }
    }
}

extern "C" void kernel_launch(void* const* d_in, const int* in_sizes, int n_in,
                              void* d_out, int out_size, void* d_ws, size_t ws_size,
                              hipStream_t stream) {
    const float* gt_padded    = (const float*)d_in[0];
    const float* prop_boxes   = (const float*)d_in[1];
    const float* pred_boxes   = (const float*)d_in[2];
    const float* class_logits = (const float*)d_in[3];
    const int*   gt_masks     = (const int*)d_in[4];
    const int*   gt_classes   = (const int*)d_in[5];

    float* out = (float*)d_out;
    float* out_cls  = out;             // classification_loss, (N, A)
    float* out_proj = out + N_ * A_;   // projection_loss,     (N, A)

    dim3 grid(N_ * A_ / 32);           // 2048 blocks = one generation
    dim3 block(256);
    cbppl_fused_kernel<<<grid, block, 0, stream>>>(
        gt_padded, prop_boxes, pred_boxes, class_logits,
        gt_masks, gt_classes, out_cls, out_proj);
}

// Round 18
// 13.723 us; speedup vs baseline: 1.1341x; 1.0879x over previous
//
#include <hip/hip_runtime.h>

// Problem constants (from reference)
#define N_ 16
#define A_ 4096
#define G_ 256
#define C_ 80
#define BIG_ 1e8f
#define LN2_ 0.69314718055994531f

// FINAL = Round 15 exact (champion, 13.64us, absmax 0.0).
// Structure: 2048 blocks x 256 threads (one co-resident generation:
// 8 blocks/CU x 4 waves = 32 waves/CU = 8 waves/SIMD at the natural
// 64-VGPR allocation; launch_bounds min-waves MUST stay 4 — asking for 8
// forces VGPR=32 and spills, R13/R14). 32 anchors/block, 16 groups x 2
// serial passes; per pass: early loads (pb + 5 logits hoisted; latency
// hides under staging/argmin) -> register-resident 16-box local argmin ->
// 4-stage DPP butterfly argmin (lexicographic (d,idx), exact
// first-occurrence jnp.argmin) -> branchless focal (closed-form negative
// class + owner-lane target correction from registers) -> DPP sum.
// Masked-out gt boxes staged as (BIG,...): never win; nonempty <=> dmin<BIG.
// Falsified levers (do not retry): issue-trim (R8), VMEM compress (R11),
// launch_bounds occupancy (R13/14), LDS-halving under 64-VGPR cap (R16/17).

#define DPP_XOR1  0xB1   // quad_perm(1,0,3,2)
#define DPP_XOR2  0x4E   // quad_perm(2,3,0,1)
#define DPP_XOR7  0x141  // row_half_mirror
#define DPP_XOR15 0x140  // row_mirror

template<int CTRL>
__device__ __forceinline__ float dppf(float x) {
    return __int_as_float(__builtin_amdgcn_update_dpp(
        0, __float_as_int(x), CTRL, 0xF, 0xF, true));
}
template<int CTRL>
__device__ __forceinline__ int dppi(int x) {
    return __builtin_amdgcn_update_dpp(0, x, CTRL, 0xF, 0xF, true);
}

template<int CTRL>
__device__ __forceinline__ void argmin_stage(float& d, int& idx) {
    const float od = dppf<CTRL>(d);
    const int   oc = dppi<CTRL>(idx);
    const bool  bt = (od < d) || (od == d && oc < idx);
    d   = bt ? od : d;
    idx = bt ? oc : idx;
}

__global__ __launch_bounds__(256, 4) void cbppl_fused_kernel(
    const float* __restrict__ gt_padded,    // (N, G, 4)
    const float* __restrict__ prop_boxes,   // (N, A, 4)
    const float* __restrict__ pred_boxes,   // (N, A, 4)
    const float* __restrict__ class_logits, // (N, A, C)
    const int*   __restrict__ gt_masks,     // (N, G) bool->int32
    const int*   __restrict__ gt_classes,   // (N, G)
    float* __restrict__ out_cls,            // (N, A)
    float* __restrict__ out_proj)           // (N, A)
{
    __shared__ float4 s_gt[G_];
    __shared__ int    s_cls[G_];

    const int t   = threadIdx.x;
    const int sub = t & 15;                  // lane-in-group
    const int gid = t >> 4;                  // group 0..15 within block
    const int n   = blockIdx.x >> 7;         // 128 blocks per batch
    const int ab  = (blockIdx.x & 127) << 5; // 32 anchors per block

    // ---- one-time: stage masked gt boxes + classes to LDS ----
    {
        const int gidx = n * G_ + t;        // t == g (256 threads)
        float4 g4 = ((const float4*)gt_padded)[gidx];
        if (!gt_masks[gidx]) { g4.x = BIG_; g4.y = BIG_; g4.z = BIG_; g4.w = BIG_; }
        s_gt[t]  = g4;
        s_cls[t] = gt_classes[gidx];
    }
    __syncthreads();

    // ---- one-time: register-cache 16 boxes per lane (interleaved) ----
    float4 b[16];
    #pragma unroll
    for (int m = 0; m < 16; ++m) b[m] = s_gt[sub + (m << 4)];

    // ---- 2 passes: 16 anchors per pass (one per 16-lane group) ----
    for (int p = 0; p < 2; ++p) {
        const int ai  = (p << 4) + gid;
        const int row = n * A_ + ab + ai;

        const float4 pb = ((const float4*)prop_boxes)[row];   // group-broadcast
        const float4 qb = ((const float4*)pred_boxes)[row];

        // 5 logit loads issued early (independent of argmin)
        const float* lrow = class_logits + (size_t)row * C_;
        float xv[5];
        #pragma unroll
        for (int k = 0; k < 5; ++k) xv[k] = lrow[sub + (k << 4)];

        // local argmin over this lane's 16 register boxes
        float dloc = INFINITY;
        int   mloc = 0;
        #pragma unroll
        for (int m = 0; m < 16; ++m) {
            const float d = fabsf(pb.x - b[m].x) + fabsf(pb.y - b[m].y)
                          + fabsf(pb.z - b[m].z) + fabsf(pb.w - b[m].w);
            if (d < dloc) { dloc = d; mloc = m; }  // lower m = lower g
        }
        int iloc = (mloc << 4) + sub;              // g index

        // 16-lane argmin butterfly on DPP (VALU pipe, no LDS)
        argmin_stage<DPP_XOR1 >(dloc, iloc);
        argmin_stage<DPP_XOR2 >(dloc, iloc);
        argmin_stage<DPP_XOR7 >(dloc, iloc);
        argmin_stage<DPP_XOR15>(dloc, iloc);
        const int   closest  = iloc;
        const int   nonempty = (dloc < BIG_);

        // epilogue lookups: uniform per group -> LDS broadcast
        const float4 cb     = s_gt[closest];
        const int    target = s_cls[closest];
        const float  pd = fabsf(qb.x - cb.x) + fabsf(qb.y - cb.y)
                        + fabsf(qb.z - cb.z) + fabsf(qb.w - cb.w);

        // focal, negative-class closed form (branchless; exact identities)
        float acc = 0.0f;
        #pragma unroll
        for (int j = 0; j < 5; ++j) {
            const float x  = xv[j];
            const float u  = __expf(-x);
            const float tt = 1.0f + u;
            const float sp = fmaf(LN2_, __log2f(tt), x);
            const float r  = __builtin_amdgcn_rcpf(tt);
            acc = fmaf(sp, r * r, acc);
        }
        acc *= 0.75f;

        // target-class correction; xt selected from registers (kt uniform)
        {
            const int kt = target >> 4;
            float xt = xv[0];
            xt = (kt == 1) ? xv[1] : xt;
            xt = (kt == 2) ? xv[2] : xt;
            xt = (kt == 3) ? xv[3] : xt;
            xt = (kt == 4) ? xv[4] : xt;
            const float u  = __expf(-xt);
            const float tt = 1.0f + u;
            const float sp = fmaf(LN2_, __log2f(tt), xt);
            const float pp = __builtin_amdgcn_rcpf(tt);
            const float q  = 1.0f - pp;
            const float corr = fmaf(0.25f * (sp - xt), q * q,
                                    -0.75f * sp * pp * pp);
            acc += ((target & 15) == sub) ? corr : 0.0f;  // owner lane adds
        }

        // group sum of focal partials on DPP
        acc += dppf<DPP_XOR1 >(acc);
        acc += dppf<DPP_XOR2 >(acc);
        acc += dppf<DPP_XOR7 >(acc);
        acc += dppf<DPP_XOR15>(acc);

        if (sub == 0) {
            out_cls[row]  = nonempty ? acc * (1.0f / (float)C_) : 0.0f;
            out_proj[row] = nonempty ? pd : 0.0f;
        }
    }
}

extern "C" void kernel_launch(void* const* d_in, const int* in_sizes, int n_in,
                              void* d_out, int out_size, void* d_ws, size_t ws_size,
                              hipStream_t stream) {
    const float* gt_padded    = (const float*)d_in[0];
    const float* prop_boxes   = (const float*)d_in[1];
    const float* pred_boxes   = (const float*)d_in[2];
    const float* class_logits = (const float*)d_in[3];
    const int*   gt_masks     = (const int*)d_in[4];
    const int*   gt_classes   = (const int*)d_in[5];

    float* out = (float*)d_out;
    float* out_cls  = out;             // classification_loss, (N, A)
    float* out_proj = out + N_ * A_;   // projection_loss,     (N, A)

    dim3 grid(N_ * A_ / 32);           // 2048 blocks = one generation
    dim3 block(256);                   // 4 waves; 8 blocks/CU -> 8 waves/SIMD
    cbppl_fused_kernel<<<grid, block, 0, stream>>>(
        gt_padded, prop_boxes, pred_boxes, class_logits,
        gt_masks, gt_classes, out_cls, out_proj);
}